// Round 16
// baseline (1440.280 us; speedup 1.0000x reference)
//
#include <hip/hip_runtime.h>
#include <hip/hip_bf16.h>

#define NS    16384
#define NF1c  2000
#define NF2c  10000
#define NH    512
#define KC    19
#define NREC  12000
#define NRECP 12032

typedef short bf16x8 __attribute__((ext_vector_type(8)));
typedef float f32x4  __attribute__((ext_vector_type(4)));

__device__ __forceinline__ unsigned short f2bf(float x) {
    return __builtin_bit_cast(unsigned short, __hip_bfloat16(x));
}
__device__ __forceinline__ float bf2f(unsigned short h) {
    return __builtin_bit_cast(float, (unsigned int)h << 16);
}

// raw barrier WITHOUT the __syncthreads vmcnt drain (T4)
__device__ __forceinline__ void sync_nodrain() {
    asm volatile("s_waitcnt lgkmcnt(0)" ::: "memory");
    __builtin_amdgcn_s_barrier();
    asm volatile("" ::: "memory");
}

// LDS chunk swizzle. BK=32 (64B rows): (r>>1)&3. BK=64 (128B rows): r&7.
// Both measured 0 SQ_LDS_BANK_CONFLICT across rounds 1-15.
template<int BK> __device__ __forceinline__ int swz(int r) {
    return (BK == 32) ? ((r >> 1) & 3) : (r & 7);
}

// async global->LDS DMA, 16B/lane; LDS dest = wave-uniform base + lane*16.
__device__ __forceinline__ void gload16(const unsigned short* g, unsigned short* l) {
    __builtin_amdgcn_global_load_lds(
        (const __attribute__((address_space(1))) void*)g,
        (__attribute__((address_space(3))) void*)l, 16, 0, 0);
}

// ---------------- consolidated prep (replaces 7 launches) ----------------
// item ranges: [0,C1) wr1b cvt | [C1,C2) wa1b cvt | [C2,C3) wd4b cvt+rowpad |
// [C3,C4) s/t for 3 BNs | [C4,C5) mflag zero (float4)
#define C1 128000L            // 512 * (2000/8)
#define C2 768000L            // + 512 * (10000/8)
#define C3 1538048L           // + 12032 * (512/8)
#define C4 1539584L           // + 3*512
#define C5 1547776L           // + 2*16384/4
__global__ void k_prep(const float* __restrict__ W_r1, unsigned short* __restrict__ wr1b,
                       const float* __restrict__ W_a1, unsigned short* __restrict__ wa1b,
                       const float* __restrict__ W_d4, unsigned short* __restrict__ wd4b,
                       const float* __restrict__ g_r, const float* __restrict__ be_r,
                       const float* __restrict__ m_r, const float* __restrict__ v_r,
                       const float* __restrict__ b_r1,
                       const float* __restrict__ g_a, const float* __restrict__ be_a,
                       const float* __restrict__ m_a, const float* __restrict__ v_a,
                       const float* __restrict__ b_a1,
                       const float* __restrict__ g_d, const float* __restrict__ be_d,
                       const float* __restrict__ m_d, const float* __restrict__ v_d,
                       const float* __restrict__ b_d1,
                       float* __restrict__ st, float* __restrict__ mflag)
{
    long i = (long)blockIdx.x * blockDim.x + threadIdx.x;
    const long stp = (long)gridDim.x * blockDim.x;
    for (; i < C5; i += stp) {
        if (i < C2) {                           // weight cvt (full rows)
            const float* src; unsigned short* dst; long j; int kp8;
            if (i < C1) { src = W_r1; dst = wr1b; j = i;      kp8 = NF1c / 8; }
            else        { src = W_a1; dst = wa1b; j = i - C1; kp8 = NF2c / 8; }
            const long row = j / kp8;
            const int  col = (int)(j - row * kp8) * 8;
            const float* p = src + row * (long)(kp8 * 8) + col;
            float4 f0 = *(const float4*)p;
            float4 f1 = *(const float4*)(p + 4);
            __align__(16) unsigned short u[8];
            u[0] = f2bf(f0.x); u[1] = f2bf(f0.y); u[2] = f2bf(f0.z); u[3] = f2bf(f0.w);
            u[4] = f2bf(f1.x); u[5] = f2bf(f1.y); u[6] = f2bf(f1.z); u[7] = f2bf(f1.w);
            *(uint4*)(dst + row * (long)(kp8 * 8) + col) = *(uint4*)u;
        } else if (i < C3) {                    // wd4b cvt with row pad
            const long j = i - C2;
            const long row = j >> 6;            // 512/8 = 64 chunks per row
            const int  col = (int)(j & 63) * 8;
            __align__(16) unsigned short u[8] = {0, 0, 0, 0, 0, 0, 0, 0};
            if (row < NREC) {
                const float* p = W_d4 + row * (long)NH + col;
                float4 f0 = *(const float4*)p;
                float4 f1 = *(const float4*)(p + 4);
                u[0] = f2bf(f0.x); u[1] = f2bf(f0.y); u[2] = f2bf(f0.z); u[3] = f2bf(f0.w);
                u[4] = f2bf(f1.x); u[5] = f2bf(f1.y); u[6] = f2bf(f1.z); u[7] = f2bf(f1.w);
            }
            *(uint4*)(wd4b + row * (long)NH + col) = *(uint4*)u;
        } else if (i < C4) {                    // BN scale/shift
            const int j = (int)(i - C3);
            const int which = j >> 9, o = j & 511;
            const float *g, *be, *m, *v, *b1;
            if (which == 0)      { g = g_r; be = be_r; m = m_r; v = v_r; b1 = b_r1; }
            else if (which == 1) { g = g_a; be = be_a; m = m_a; v = v_a; b1 = b_a1; }
            else                 { g = g_d; be = be_d; m = m_d; v = v_d; b1 = b_d1; }
            const float sc = g[o] * rsqrtf(v[o] + 1e-5f);
            st[which * 2 * NH + o]      = sc;
            st[which * 2 * NH + NH + o] = be[o] + (b1[o] - m[o]) * sc;
        } else {                                // mflag zero
            const long j = i - C4;
            ((float4*)mflag)[j] = make_float4(0.f, 0.f, 0.f, 0.f);
        }
    }
}

// -------- fused encoder GEMMs: r4-exact body, atac+rna in one launch --------
// 1024 blocks; after XCD swizzle, which = L&1 (even=atac K=10000, odd=rna
// K=2000). Per XCD: 64 atac + 64 rna blocks interleaved -> staggered
// finish times; short rna blocks free slots mid-launch so resident blocks
// desynchronize (m114 inter-block overlap), unlike two lockstepped launches.
__global__ __launch_bounds__(256)
void k_encf(const float* __restrict__ A_a, const float* __restrict__ A_r,
            const unsigned short* __restrict__ B_a, const unsigned short* __restrict__ B_r,
            const float* __restrict__ st,
            unsigned short* __restrict__ H_a, unsigned short* __restrict__ H_r)
{
    constexpr int BK = 64;
    constexpr int JC = BK / 16;
    __shared__ __align__(16) unsigned short As[2][128 * BK];
    __shared__ __align__(16) unsigned short Bs[2][128 * BK];

    const int q8 = gridDim.x >> 3;          // 1024/8 = 128
    const int L  = (blockIdx.x & 7) * q8 + (blockIdx.x >> 3);
    const int which = L & 1;                // 0 = atac, 1 = rna
    const int inner = L >> 1;               // 0..511
    const int tn = inner & 3, tm = inner >> 2;

    const float*          Ag = which ? A_r : A_a;
    const unsigned short* Bg = which ? B_r : B_a;
    const int K = which ? NF1c : NF2c;
    const float* sc = st + (which ? 0 : 2 * NH);        // st: [r s,t][a s,t][d s,t]
    const float* sh = sc + NH;
    unsigned short* Hout = which ? H_r : H_a;

    const int tid  = threadIdx.x;
    const int wave = tid >> 6, lane = tid & 63;
    const int wr   = wave >> 1, wc = wave & 1;
    const int lo   = lane & 15, hi = lane >> 4;
    const int srow = tid >> 1, shalf = tid & 1;

    const float*          Af = Ag + (size_t)(tm * 128 + srow) * K;
    const unsigned short* Bp = Bg + (size_t)(tn * 128 + srow) * K;

    f32x4 acc[4][4];
#pragma unroll
    for (int i = 0; i < 4; i++)
#pragma unroll
        for (int j = 0; j < 4; j++) acc[i][j] = (f32x4){0.f, 0.f, 0.f, 0.f};

    float4 rfa[BK / 8];
    uint4  rb[JC];

    auto issue = [&](int k0, bool tail) {
        const int kb = k0 + shalf * (BK / 2);
        if (!tail) {
#pragma unroll
            for (int q = 0; q < BK / 8; q++) rfa[q] = *(const float4*)(Af + kb + q * 4);
#pragma unroll
            for (int j = 0; j < JC; j++) rb[j] = *(const uint4*)(Bp + kb + j * 8);
        } else {
#pragma unroll
            for (int q = 0; q < BK / 8; q++) {
                float4 f;
                f.x = (kb + q * 4 + 0 < K) ? Af[kb + q * 4 + 0] : 0.f;
                f.y = (kb + q * 4 + 1 < K) ? Af[kb + q * 4 + 1] : 0.f;
                f.z = (kb + q * 4 + 2 < K) ? Af[kb + q * 4 + 2] : 0.f;
                f.w = (kb + q * 4 + 3 < K) ? Af[kb + q * 4 + 3] : 0.f;
                rfa[q] = f;
            }
#pragma unroll
            for (int j = 0; j < JC; j++) {
                __align__(16) unsigned short t8[8];
#pragma unroll
                for (int e = 0; e < 8; e++)
                    t8[e] = (kb + j * 8 + e < K) ? Bp[kb + j * 8 + e] : (unsigned short)0;
                rb[j] = *(uint4*)t8;
            }
        }
    };

    auto write = [&](int buf) {
        char* Ap = (char*)As[buf];
        char* Bq = (char*)Bs[buf];
        const int rbase = srow * (2 * BK);
        const int sw = swz<BK>(srow);
#pragma unroll
        for (int j = 0; j < JC; j++) {
            const int c = shalf * JC + j;
            const int pos = rbase + ((c ^ sw) << 4);
            uint4 av;
            unsigned int* w32 = (unsigned int*)&av;
            const float* fp = (const float*)&rfa[2 * j];
#pragma unroll
            for (int e = 0; e < 4; e++) {
                unsigned int l16 = f2bf(fp[2 * e]);
                unsigned int h16 = f2bf(fp[2 * e + 1]);
                w32[e] = l16 | (h16 << 16);
            }
            *(uint4*)(Ap + pos) = av;
            *(uint4*)(Bq + pos) = rb[j];
        }
    };

    auto comp = [&](int buf) {
        const char* Ap = (const char*)As[buf];
        const char* Bq = (const char*)Bs[buf];
#pragma unroll
        for (int s = 0; s < BK / 32; s++) {
            bf16x8 af[4], bfv[4];
#pragma unroll
            for (int f = 0; f < 4; f++) {
                const int ar = wr * 64 + f * 16 + lo;
                af[f]  = *(const bf16x8*)(Ap + ar * (2 * BK) + (((s * 4 + hi) ^ swz<BK>(ar)) << 4));
                const int br = wc * 64 + f * 16 + lo;
                bfv[f] = *(const bf16x8*)(Bq + br * (2 * BK) + (((s * 4 + hi) ^ swz<BK>(br)) << 4));
            }
#pragma unroll
            for (int i = 0; i < 4; i++)
#pragma unroll
                for (int j = 0; j < 4; j++)
                    acc[i][j] = __builtin_amdgcn_mfma_f32_16x16x32_bf16(af[i], bfv[j], acc[i][j], 0, 0, 0);
        }
    };

    const int ntf = K / BK;
    const bool rem = (K % BK) != 0;
    const int nt = ntf + (rem ? 1 : 0);
    issue(0, rem && nt == 1);
    for (int t = 0; t < nt; ++t) {
        write(t & 1);
        if (t + 1 < nt) issue((t + 1) * BK, rem && (t + 1 == nt - 1));
        sync_nodrain();
        comp(t & 1);
    }

#pragma unroll
    for (int i = 0; i < 4; i++) {
#pragma unroll
        for (int j = 0; j < 4; j++) {
            const int col = tn * 128 + wc * 64 + j * 16 + lo;
#pragma unroll
            for (int r = 0; r < 4; r++) {
                const long row = (long)tm * 128 + wr * 64 + i * 16 + hi * 4 + r;
                float v = fmaxf(acc[i][j][r] * sc[col] + sh[col], 0.f);
                Hout[row * NH + col] = f2bf(v);
            }
        }
    }
}

// -------- recon GEMM (r15-exact): 256x256, 8 waves, DMA, NT stores --------
__global__ __launch_bounds__(512)
void k_rec256(const unsigned short* __restrict__ A, const unsigned short* __restrict__ B,
              const float* __restrict__ bias, float* __restrict__ Fout)
{
    __shared__ __align__(16) unsigned short As[2][256 * 32];
    __shared__ __align__(16) unsigned short Bs[2][256 * 32];

    const int q8 = gridDim.x >> 3;             // 3008 % 8 == 0
    const int L  = (blockIdx.x & 7) * q8 + (blockIdx.x >> 3);
    const int tn = L % 47, tm = L / 47;

    const int tid  = threadIdx.x;
    const int w    = tid >> 6, lane = tid & 63;
    const int wm   = w >> 2, wn = w & 3;
    const int lo   = lane & 15, hi = lane >> 4;

    const int rl0 = w * 32 + (lane >> 2);
    const int sch = ((lane & 3) ^ ((lane >> 3) & 3)) * 8;
    const unsigned short* Adma = A + (size_t)(tm * 256 + rl0) * NH + sch;
    const unsigned short* Bdma = B + (size_t)(tn * 256 + rl0) * NH + sch;

    f32x4 acc[8][4];
#pragma unroll
    for (int i = 0; i < 8; i++)
#pragma unroll
        for (int j = 0; j < 4; j++) acc[i][j] = (f32x4){0.f, 0.f, 0.f, 0.f};

    auto issue = [&](int buf, int kt) {
        const int ko = kt * 32;
        gload16(Adma + ko,            &As[buf][(w * 32) * 32]);
        gload16(Adma + 16 * NH + ko,  &As[buf][(w * 32 + 16) * 32]);
        gload16(Bdma + ko,            &Bs[buf][(w * 32) * 32]);
        gload16(Bdma + 16 * NH + ko,  &Bs[buf][(w * 32 + 16) * 32]);
    };
    auto ldA = [&](int buf, int fm) -> bf16x8 {
        const int ar = wm * 128 + fm * 16 + lo;
        return *(const bf16x8*)((const char*)As[buf] + ar * 64 + ((hi ^ ((ar >> 1) & 3)) << 4));
    };
    auto ldB = [&](int buf, int fn) -> bf16x8 {
        const int br = wn * 64 + fn * 16 + lo;
        return *(const bf16x8*)((const char*)Bs[buf] + br * 64 + ((hi ^ ((br >> 1) & 3)) << 4));
    };

    const int nt = NH / 32;    // 16
    issue(0, 0);
    asm volatile("s_waitcnt vmcnt(0)" ::: "memory");
    __builtin_amdgcn_s_barrier();
    asm volatile("" ::: "memory");

    for (int kt = 0; kt < nt; ++kt) {
        const int cur = kt & 1;
        const bool more = (kt + 1 < nt);
        if (more) issue(cur ^ 1, kt + 1);
        bf16x8 bf[4], a0, a1, a2, a3;
#pragma unroll
        for (int fn = 0; fn < 4; fn++) bf[fn] = ldB(cur, fn);
        a0 = ldA(cur, 0); a1 = ldA(cur, 1); a2 = ldA(cur, 2); a3 = ldA(cur, 3);
        asm volatile("s_waitcnt lgkmcnt(0)" ::: "memory");
        __builtin_amdgcn_s_setprio(1);
#pragma unroll
        for (int fn = 0; fn < 4; fn++) {
            acc[0][fn] = __builtin_amdgcn_mfma_f32_16x16x32_bf16(a0, bf[fn], acc[0][fn], 0, 0, 0);
            acc[1][fn] = __builtin_amdgcn_mfma_f32_16x16x32_bf16(a1, bf[fn], acc[1][fn], 0, 0, 0);
            acc[2][fn] = __builtin_amdgcn_mfma_f32_16x16x32_bf16(a2, bf[fn], acc[2][fn], 0, 0, 0);
            acc[3][fn] = __builtin_amdgcn_mfma_f32_16x16x32_bf16(a3, bf[fn], acc[3][fn], 0, 0, 0);
        }
        __builtin_amdgcn_s_setprio(0);
        a0 = ldA(cur, 4); a1 = ldA(cur, 5); a2 = ldA(cur, 6); a3 = ldA(cur, 7);
        asm volatile("s_waitcnt lgkmcnt(0)" ::: "memory");
        __builtin_amdgcn_s_setprio(1);
#pragma unroll
        for (int fn = 0; fn < 4; fn++) {
            acc[4][fn] = __builtin_amdgcn_mfma_f32_16x16x32_bf16(a0, bf[fn], acc[4][fn], 0, 0, 0);
            acc[5][fn] = __builtin_amdgcn_mfma_f32_16x16x32_bf16(a1, bf[fn], acc[5][fn], 0, 0, 0);
            acc[6][fn] = __builtin_amdgcn_mfma_f32_16x16x32_bf16(a2, bf[fn], acc[6][fn], 0, 0, 0);
            acc[7][fn] = __builtin_amdgcn_mfma_f32_16x16x32_bf16(a3, bf[fn], acc[7][fn], 0, 0, 0);
        }
        __builtin_amdgcn_s_setprio(0);
        if (more) {
            asm volatile("s_waitcnt vmcnt(0)" ::: "memory");
            __builtin_amdgcn_s_barrier();
            asm volatile("" ::: "memory");
        }
    }

    // nontemporal epilogue stores (output never re-read on device)
#pragma unroll
    for (int fm = 0; fm < 8; fm++) {
#pragma unroll
        for (int fn = 0; fn < 4; fn++) {
            const int col = tn * 256 + wn * 64 + fn * 16 + lo;
#pragma unroll
            for (int r = 0; r < 4; r++) {
                const long row = (long)tm * 256 + wm * 128 + fm * 16 + hi * 4 + r;
                if (col < NREC)
                    __builtin_nontemporal_store(acc[fm][fn][r] + bias[col],
                                                &Fout[row * (long)NREC + col]);
            }
        }
    }
}

// ---------------- stage C: projections + scatter ----------------
__global__ __launch_bounds__(256)
void k_proj(const unsigned short* __restrict__ h_rna,
            const unsigned short* __restrict__ h_atac,
            const float* __restrict__ W_rmu, const float* __restrict__ b_rmu,
            const float* __restrict__ W_rvar, const float* __restrict__ b_rvar,
            const float* __restrict__ W_amu, const float* __restrict__ b_amu,
            const float* __restrict__ W_avar, const float* __restrict__ b_avar,
            const int* __restrict__ idx_rna, const int* __restrict__ idx_atac,
            float* __restrict__ mu0, float* __restrict__ var0,
            float* __restrict__ mu1, float* __restrict__ var1,
            float* __restrict__ mflag)
{
    __shared__ __align__(16) unsigned short hsh[4][2][NH];
    const int wave = threadIdx.x >> 6, lane = threadIdx.x & 63;
    const long i = (long)blockIdx.x * 4 + wave;
    *(uint4*)&hsh[wave][0][lane * 8] = *(const uint4*)(h_rna  + i * NH + lane * 8);
    *(uint4*)&hsh[wave][1][lane * 8] = *(const uint4*)(h_atac + i * NH + lane * 8);
    __syncthreads();
    const int mod = lane >> 5, oo = lane & 31;
    const int isv = oo >> 4, o = oo & 15;
    const float *W, *bias;
    if (mod == 0) { W = isv ? W_rvar : W_rmu; bias = isv ? b_rvar : b_rmu; }
    else          { W = isv ? W_avar : W_amu; bias = isv ? b_avar : b_amu; }
    const unsigned short* hr = hsh[wave][mod];
    const float* wrow = W + o * NH;
    float a = 0.f;
#pragma unroll 4
    for (int k = 0; k < NH; k += 4) {
        float4 w = *(const float4*)(wrow + k);
        a += bf2f(hr[k]) * w.x + bf2f(hr[k+1]) * w.y + bf2f(hr[k+2]) * w.z + bf2f(hr[k+3]) * w.w;
    }
    a += bias[o];
    const int tgt = (mod == 0) ? idx_rna[i] : idx_atac[i];
    float* mu  = mod ? mu1  : mu0;
    float* var = mod ? var1 : var0;
    if (!isv) mu[(long)tgt * 16 + o] = a;
    else      var[(long)tgt * 16 + o] = expf(a);
    if (oo == 0) mflag[(long)mod * NS + tgt] = 1.f;
}

// ---------------- stage C: PoE combine + q + decoder hidden ----------------
__global__ __launch_bounds__(256)
void k_combine(const float* __restrict__ mu0, const float* __restrict__ var0,
               const float* __restrict__ mu1, const float* __restrict__ var1,
               const float* __restrict__ mflag,
               const float* __restrict__ eps, const float* __restrict__ cluster,
               const float* __restrict__ W_d1,
               const float* __restrict__ s_d, const float* __restrict__ t_d,
               float* __restrict__ o_zmu, float* __restrict__ o_zvar,
               float* __restrict__ o_z, float* __restrict__ o_q,
               unsigned short* __restrict__ h_d)
{
    __shared__ float zsh[4][16];
    const int wave = threadIdx.x >> 6, lane = threadIdx.x & 63;
    const long i = (long)blockIdx.x * 4 + wave;
    if (lane < 16) {
        const int d = lane;
        const float f0 = mflag[i], f1 = mflag[NS + i];
        float ts = 1.f, num = 0.f;
        if (f0 != 0.f) { float iv = 1.f / var0[i*16+d]; ts += iv; num += mu0[i*16+d] * iv; }
        if (f1 != 0.f) { float iv = 1.f / var1[i*16+d]; ts += iv; num += mu1[i*16+d] * iv; }
        const float zm = num / ts, zv = 1.f / ts;
        const float z = zm + zv * eps[i*16+d];
        o_zmu[i*16+d] = zm; o_zvar[i*16+d] = zv; o_z[i*16+d] = z;
        zsh[wave][d] = z;
    }
    __syncthreads();
    float zreg[16];
#pragma unroll
    for (int d = 0; d < 16; d++) zreg[d] = zsh[wave][d];
    float qk = 0.f;
    if (lane < KC) {
        float d2 = 0.f;
#pragma unroll
        for (int d = 0; d < 16; d++) { float df = zreg[d] - cluster[lane*16+d]; d2 += df*df; }
        qk = 1.f / (1.f + d2);
    }
    float ssum = qk;
#pragma unroll
    for (int off = 16; off > 0; off >>= 1) ssum += __shfl_xor(ssum, off, 32);
    if (lane < KC) o_q[i * KC + lane] = qk / ssum;
#pragma unroll
    for (int j = 0; j < 8; j++) {
        const int c = lane + 64 * j;
        float a = 0.f;
#pragma unroll
        for (int d = 0; d < 16; d += 4) {
            float4 w = *(const float4*)(W_d1 + c * 16 + d);
            a += zreg[d] * w.x + zreg[d+1] * w.y + zreg[d+2] * w.z + zreg[d+3] * w.w;
        }
        a = fmaxf(a * s_d[c] + t_d[c], 0.f);
        h_d[i * NH + c] = f2bf(a);
    }
}

// ---------------- launcher ----------------
extern "C" void kernel_launch(void* const* d_in, const int* in_sizes, int n_in,
                              void* d_out, int out_size, void* d_ws, size_t ws_size,
                              hipStream_t stream)
{
    const float* rna    = (const float*)d_in[0];
    const float* atac   = (const float*)d_in[1];
    const int*   i_rna  = (const int*)d_in[2];
    const int*   i_atac = (const int*)d_in[3];
    const float* eps    = (const float*)d_in[4];
    const float* W_r1   = (const float*)d_in[5];
    const float* b_r1   = (const float*)d_in[6];
    const float* g_r    = (const float*)d_in[7];
    const float* be_r   = (const float*)d_in[8];
    const float* m_r    = (const float*)d_in[9];
    const float* v_r    = (const float*)d_in[10];
    const float* W_rmu  = (const float*)d_in[11];
    const float* b_rmu  = (const float*)d_in[12];
    const float* W_rvar = (const float*)d_in[13];
    const float* b_rvar = (const float*)d_in[14];
    const float* W_a1   = (const float*)d_in[15];
    const float* b_a1   = (const float*)d_in[16];
    const float* g_a    = (const float*)d_in[17];
    const float* be_a   = (const float*)d_in[18];
    const float* m_a    = (const float*)d_in[19];
    const float* v_a    = (const float*)d_in[20];
    const float* W_amu  = (const float*)d_in[21];
    const float* b_amu  = (const float*)d_in[22];
    const float* W_avar = (const float*)d_in[23];
    const float* b_avar = (const float*)d_in[24];
    const float* W_d1   = (const float*)d_in[25];
    const float* b_d1   = (const float*)d_in[26];
    const float* g_d    = (const float*)d_in[27];
    const float* be_d   = (const float*)d_in[28];
    const float* m_d    = (const float*)d_in[29];
    const float* v_d    = (const float*)d_in[30];
    const float* W_d4   = (const float*)d_in[31];
    const float* b_d4   = (const float*)d_in[32];
    const float* clus   = (const float*)d_in[33];
    (void)in_sizes; (void)n_in; (void)out_size;

    char* w = (char*)d_ws;
    size_t off = 0;
    auto carve = [&](size_t bytes) { void* p = w + off; off += (bytes + 255) & ~(size_t)255; return p; };
    unsigned short* wr1b  = (unsigned short*)carve((size_t)NH * NF1c * 2);
    unsigned short* wa1b  = (unsigned short*)carve((size_t)NH * NF2c * 2);
    unsigned short* wd4b  = (unsigned short*)carve((size_t)NRECP * NH * 2);
    unsigned short* hrna  = (unsigned short*)carve((size_t)NS * NH * 2);
    unsigned short* hatac = (unsigned short*)carve((size_t)NS * NH * 2);
    unsigned short* hd    = (unsigned short*)carve((size_t)NS * NH * 2);
    float* mu0   = (float*)carve((size_t)NS * 16 * 4);
    float* var0  = (float*)carve((size_t)NS * 16 * 4);
    float* mu1   = (float*)carve((size_t)NS * 16 * 4);
    float* var1  = (float*)carve((size_t)NS * 16 * 4);
    float* mflag = (float*)carve((size_t)2 * NS * 4);
    float* st    = (float*)carve((size_t)6 * NH * 4);
    if (off > ws_size) return;  // insufficient workspace -> loud validation failure

    // st layout: [r: s,t][a: s,t][d: s,t]
    float* s_a = st + 2 * NH; float* t_a = st + 3 * NH;
    float* s_d = st + 4 * NH; float* t_d = st + 5 * NH;
    (void)s_a; (void)t_a;

    float* out    = (float*)d_out;
    float* o_rec  = out;
    float* o_zmu  = out + (size_t)NS * NREC;
    float* o_zvar = o_zmu + (size_t)NS * 16;
    float* o_z    = o_zvar + (size_t)NS * 16;
    float* o_q    = o_z + (size_t)NS * 16;

    dim3 blk(256);
    // consolidated prep: one launch replaces 3x cvt + 3x prep_st + zero
    k_prep<<<4096, blk, 0, stream>>>(W_r1, wr1b, W_a1, wa1b, W_d4, wd4b,
                                     g_r, be_r, m_r, v_r, b_r1,
                                     g_a, be_a, m_a, v_a, b_a1,
                                     g_d, be_d, m_d, v_d, b_d1,
                                     st, mflag);
    // fused encoders: 1024 blocks, r4-exact body (even L = atac, odd = rna)
    k_encf<<<1024, blk, 0, stream>>>(atac, rna, wa1b, wr1b, st, hatac, hrna);
    k_proj<<<NS / 4, blk, 0, stream>>>(hrna, hatac, W_rmu, b_rmu, W_rvar, b_rvar,
                                       W_amu, b_amu, W_avar, b_avar, i_rna, i_atac,
                                       mu0, var0, mu1, var1, mflag);
    k_combine<<<NS / 4, blk, 0, stream>>>(mu0, var0, mu1, var1, mflag, eps, clus,
                                          W_d1, s_d, t_d, o_zmu, o_zvar, o_z, o_q, hd);
    // recon: 256x256 tile, 3008 blocks of 512 threads (r15-exact)
    k_rec256<<<3008, dim3(512), 0, stream>>>(hd, wd4b, b_d4, o_rec);
}

// Round 17
// 1180.348 us; speedup vs baseline: 1.2202x; 1.2202x over previous
//
#include <hip/hip_runtime.h>
#include <hip/hip_bf16.h>

#define NS    16384
#define NF1c  2000
#define NF2c  10000
#define NH    512
#define KC    19
#define NREC  12000
#define NRECP 12032

typedef short bf16x8 __attribute__((ext_vector_type(8)));
typedef float f32x4  __attribute__((ext_vector_type(4)));

__device__ __forceinline__ unsigned short f2bf(float x) {
    return __builtin_bit_cast(unsigned short, __hip_bfloat16(x));
}
__device__ __forceinline__ float bf2f(unsigned short h) {
    return __builtin_bit_cast(float, (unsigned int)h << 16);
}

// raw barrier WITHOUT the __syncthreads vmcnt drain (T4)
__device__ __forceinline__ void sync_nodrain() {
    asm volatile("s_waitcnt lgkmcnt(0)" ::: "memory");
    __builtin_amdgcn_s_barrier();
    asm volatile("" ::: "memory");
}

// LDS chunk swizzle. BK=32 (64B rows): (r>>1)&3. BK=64 (128B rows): r&7.
// Both measured 0 SQ_LDS_BANK_CONFLICT across rounds 1-16.
template<int BK> __device__ __forceinline__ int swz(int r) {
    return (BK == 32) ? ((r >> 1) & 3) : (r & 7);
}

// async global->LDS DMA, 16B/lane; LDS dest = wave-uniform base + lane*16.
__device__ __forceinline__ void gload16(const unsigned short* g, unsigned short* l) {
    __builtin_amdgcn_global_load_lds(
        (const __attribute__((address_space(1))) void*)g,
        (__attribute__((address_space(3))) void*)l, 16, 0, 0);
}

// ---------------- consolidated prep (one launch, r16-verified ~45us win) ----
// item ranges: [0,C1) wr1b cvt | [C1,C2) wa1b cvt | [C2,C3) wd4b cvt+rowpad |
// [C3,C4) s/t for 3 BNs | [C4,C5) mflag zero (float4)
#define C1 128000L            // 512 * (2000/8)
#define C2 768000L            // + 512 * (10000/8)
#define C3 1538048L           // + 12032 * (512/8)
#define C4 1539584L           // + 3*512
#define C5 1547776L           // + 2*16384/4
__global__ void k_prep(const float* __restrict__ W_r1, unsigned short* __restrict__ wr1b,
                       const float* __restrict__ W_a1, unsigned short* __restrict__ wa1b,
                       const float* __restrict__ W_d4, unsigned short* __restrict__ wd4b,
                       const float* __restrict__ g_r, const float* __restrict__ be_r,
                       const float* __restrict__ m_r, const float* __restrict__ v_r,
                       const float* __restrict__ b_r1,
                       const float* __restrict__ g_a, const float* __restrict__ be_a,
                       const float* __restrict__ m_a, const float* __restrict__ v_a,
                       const float* __restrict__ b_a1,
                       const float* __restrict__ g_d, const float* __restrict__ be_d,
                       const float* __restrict__ m_d, const float* __restrict__ v_d,
                       const float* __restrict__ b_d1,
                       float* __restrict__ st, float* __restrict__ mflag)
{
    long i = (long)blockIdx.x * blockDim.x + threadIdx.x;
    const long stp = (long)gridDim.x * blockDim.x;
    for (; i < C5; i += stp) {
        if (i < C2) {                           // weight cvt (full rows)
            const float* src; unsigned short* dst; long j; int kp8;
            if (i < C1) { src = W_r1; dst = wr1b; j = i;      kp8 = NF1c / 8; }
            else        { src = W_a1; dst = wa1b; j = i - C1; kp8 = NF2c / 8; }
            const long row = j / kp8;
            const int  col = (int)(j - row * kp8) * 8;
            const float* p = src + row * (long)(kp8 * 8) + col;
            float4 f0 = *(const float4*)p;
            float4 f1 = *(const float4*)(p + 4);
            __align__(16) unsigned short u[8];
            u[0] = f2bf(f0.x); u[1] = f2bf(f0.y); u[2] = f2bf(f0.z); u[3] = f2bf(f0.w);
            u[4] = f2bf(f1.x); u[5] = f2bf(f1.y); u[6] = f2bf(f1.z); u[7] = f2bf(f1.w);
            *(uint4*)(dst + row * (long)(kp8 * 8) + col) = *(uint4*)u;
        } else if (i < C3) {                    // wd4b cvt with row pad
            const long j = i - C2;
            const long row = j >> 6;            // 512/8 = 64 chunks per row
            const int  col = (int)(j & 63) * 8;
            __align__(16) unsigned short u[8] = {0, 0, 0, 0, 0, 0, 0, 0};
            if (row < NREC) {
                const float* p = W_d4 + row * (long)NH + col;
                float4 f0 = *(const float4*)p;
                float4 f1 = *(const float4*)(p + 4);
                u[0] = f2bf(f0.x); u[1] = f2bf(f0.y); u[2] = f2bf(f0.z); u[3] = f2bf(f0.w);
                u[4] = f2bf(f1.x); u[5] = f2bf(f1.y); u[6] = f2bf(f1.z); u[7] = f2bf(f1.w);
            }
            *(uint4*)(wd4b + row * (long)NH + col) = *(uint4*)u;
        } else if (i < C4) {                    // BN scale/shift
            const int j = (int)(i - C3);
            const int which = j >> 9, o = j & 511;
            const float *g, *be, *m, *v, *b1;
            if (which == 0)      { g = g_r; be = be_r; m = m_r; v = v_r; b1 = b_r1; }
            else if (which == 1) { g = g_a; be = be_a; m = m_a; v = v_a; b1 = b_a1; }
            else                 { g = g_d; be = be_d; m = m_d; v = v_d; b1 = b_d1; }
            const float sc = g[o] * rsqrtf(v[o] + 1e-5f);
            st[which * 2 * NH + o]      = sc;
            st[which * 2 * NH + NH + o] = be[o] + (b1[o] - m[o]) * sc;
        } else {                                // mflag zero
            const long j = i - C4;
            ((float4*)mflag)[j] = make_float4(0.f, 0.f, 0.f, 0.f);
        }
    }
}

// -------- encoder GEMM (r4-exact): C = A[M,K]fp32 * B[Nn,K]bf16^T --------
__global__ __launch_bounds__(256)
void k_gemm(const void* __restrict__ Aptr, const unsigned short* __restrict__ B,
            int K, int Nn, int ntn,
            const float* __restrict__ sc, const float* __restrict__ sh,
            unsigned short* __restrict__ Hout)
{
    constexpr int BK = 64;
    constexpr int JC = BK / 16;
    __shared__ __align__(16) unsigned short As[2][128 * BK];
    __shared__ __align__(16) unsigned short Bs[2][128 * BK];

    const int nwg = gridDim.x;
    const int q8  = nwg >> 3;
    const int L   = (blockIdx.x & 7) * q8 + (blockIdx.x >> 3);
    const int tn  = L % ntn, tm = L / ntn;

    const int tid  = threadIdx.x;
    const int wave = tid >> 6, lane = tid & 63;
    const int wr   = wave >> 1, wc = wave & 1;
    const int lo   = lane & 15, hi = lane >> 4;
    const int srow = tid >> 1, shalf = tid & 1;
    const long arow = (long)tm * 128 + srow;
    const int  brow = tn * 128 + srow;
    const bool bok  = (brow < Nn);

    const float*          Af = (const float*)Aptr + arow * (long)K;
    const unsigned short* Bp = B + (long)brow * K;

    f32x4 acc[4][4];
#pragma unroll
    for (int i = 0; i < 4; i++)
#pragma unroll
        for (int j = 0; j < 4; j++) acc[i][j] = (f32x4){0.f, 0.f, 0.f, 0.f};

    float4 rfa[BK / 8];
    uint4  rb[JC];

    auto issue = [&](int k0, bool tail) {
        const int kb = k0 + shalf * (BK / 2);
        if (!tail) {
#pragma unroll
            for (int q = 0; q < BK / 8; q++) rfa[q] = *(const float4*)(Af + kb + q * 4);
        } else {
#pragma unroll
            for (int q = 0; q < BK / 8; q++) {
                float4 f;
                f.x = (kb + q * 4 + 0 < K) ? Af[kb + q * 4 + 0] : 0.f;
                f.y = (kb + q * 4 + 1 < K) ? Af[kb + q * 4 + 1] : 0.f;
                f.z = (kb + q * 4 + 2 < K) ? Af[kb + q * 4 + 2] : 0.f;
                f.w = (kb + q * 4 + 3 < K) ? Af[kb + q * 4 + 3] : 0.f;
                rfa[q] = f;
            }
        }
#pragma unroll
        for (int j = 0; j < JC; j++) rb[j] = (uint4){0, 0, 0, 0};
        if (bok) {
            if (!tail) {
#pragma unroll
                for (int j = 0; j < JC; j++) rb[j] = *(const uint4*)(Bp + kb + j * 8);
            } else {
#pragma unroll
                for (int j = 0; j < JC; j++) {
                    __align__(16) unsigned short t8[8];
#pragma unroll
                    for (int e = 0; e < 8; e++)
                        t8[e] = (kb + j * 8 + e < K) ? Bp[kb + j * 8 + e] : (unsigned short)0;
                    rb[j] = *(uint4*)t8;
                }
            }
        }
    };

    auto write = [&](int buf) {
        char* Ap = (char*)As[buf];
        char* Bq = (char*)Bs[buf];
        const int rbase = srow * (2 * BK);
        const int sw = swz<BK>(srow);
#pragma unroll
        for (int j = 0; j < JC; j++) {
            const int c = shalf * JC + j;
            const int pos = rbase + ((c ^ sw) << 4);
            uint4 av;
            unsigned int* w32 = (unsigned int*)&av;
            const float* fp = (const float*)&rfa[2 * j];
#pragma unroll
            for (int e = 0; e < 4; e++) {
                unsigned int l16 = f2bf(fp[2 * e]);
                unsigned int h16 = f2bf(fp[2 * e + 1]);
                w32[e] = l16 | (h16 << 16);
            }
            *(uint4*)(Ap + pos) = av;
            *(uint4*)(Bq + pos) = rb[j];
        }
    };

    auto comp = [&](int buf) {
        const char* Ap = (const char*)As[buf];
        const char* Bq = (const char*)Bs[buf];
#pragma unroll
        for (int s = 0; s < BK / 32; s++) {
            bf16x8 af[4], bfv[4];
#pragma unroll
            for (int f = 0; f < 4; f++) {
                const int ar = wr * 64 + f * 16 + lo;
                af[f]  = *(const bf16x8*)(Ap + ar * (2 * BK) + (((s * 4 + hi) ^ swz<BK>(ar)) << 4));
                const int br = wc * 64 + f * 16 + lo;
                bfv[f] = *(const bf16x8*)(Bq + br * (2 * BK) + (((s * 4 + hi) ^ swz<BK>(br)) << 4));
            }
#pragma unroll
            for (int i = 0; i < 4; i++)
#pragma unroll
                for (int j = 0; j < 4; j++)
                    acc[i][j] = __builtin_amdgcn_mfma_f32_16x16x32_bf16(af[i], bfv[j], acc[i][j], 0, 0, 0);
        }
    };

    const int ntf = K / BK;
    const bool rem = (K % BK) != 0;
    const int nt = ntf + (rem ? 1 : 0);
    issue(0, rem && nt == 1);
    for (int t = 0; t < nt; ++t) {
        write(t & 1);
        if (t + 1 < nt) issue((t + 1) * BK, rem && (t + 1 == nt - 1));
        sync_nodrain();
        comp(t & 1);
    }

#pragma unroll
    for (int i = 0; i < 4; i++) {
#pragma unroll
        for (int j = 0; j < 4; j++) {
            const int col = tn * 128 + wc * 64 + j * 16 + lo;
#pragma unroll
            for (int r = 0; r < 4; r++) {
                const long row = (long)tm * 128 + wr * 64 + i * 16 + hi * 4 + r;
                float v = fmaxf(acc[i][j][r] * sc[col] + sh[col], 0.f);
                Hout[row * NH + col] = f2bf(v);
            }
        }
    }
}

// -------- recon GEMM (r15-exact): 256x256, 8 waves, DMA, NT stores --------
__global__ __launch_bounds__(512)
void k_rec256(const unsigned short* __restrict__ A, const unsigned short* __restrict__ B,
              const float* __restrict__ bias, float* __restrict__ Fout)
{
    __shared__ __align__(16) unsigned short As[2][256 * 32];
    __shared__ __align__(16) unsigned short Bs[2][256 * 32];

    const int q8 = gridDim.x >> 3;             // 3008 % 8 == 0
    const int L  = (blockIdx.x & 7) * q8 + (blockIdx.x >> 3);
    const int tn = L % 47, tm = L / 47;

    const int tid  = threadIdx.x;
    const int w    = tid >> 6, lane = tid & 63;
    const int wm   = w >> 2, wn = w & 3;
    const int lo   = lane & 15, hi = lane >> 4;

    const int rl0 = w * 32 + (lane >> 2);
    const int sch = ((lane & 3) ^ ((lane >> 3) & 3)) * 8;
    const unsigned short* Adma = A + (size_t)(tm * 256 + rl0) * NH + sch;
    const unsigned short* Bdma = B + (size_t)(tn * 256 + rl0) * NH + sch;

    f32x4 acc[8][4];
#pragma unroll
    for (int i = 0; i < 8; i++)
#pragma unroll
        for (int j = 0; j < 4; j++) acc[i][j] = (f32x4){0.f, 0.f, 0.f, 0.f};

    auto issue = [&](int buf, int kt) {
        const int ko = kt * 32;
        gload16(Adma + ko,            &As[buf][(w * 32) * 32]);
        gload16(Adma + 16 * NH + ko,  &As[buf][(w * 32 + 16) * 32]);
        gload16(Bdma + ko,            &Bs[buf][(w * 32) * 32]);
        gload16(Bdma + 16 * NH + ko,  &Bs[buf][(w * 32 + 16) * 32]);
    };
    auto ldA = [&](int buf, int fm) -> bf16x8 {
        const int ar = wm * 128 + fm * 16 + lo;
        return *(const bf16x8*)((const char*)As[buf] + ar * 64 + ((hi ^ ((ar >> 1) & 3)) << 4));
    };
    auto ldB = [&](int buf, int fn) -> bf16x8 {
        const int br = wn * 64 + fn * 16 + lo;
        return *(const bf16x8*)((const char*)Bs[buf] + br * 64 + ((hi ^ ((br >> 1) & 3)) << 4));
    };

    const int nt = NH / 32;    // 16
    issue(0, 0);
    asm volatile("s_waitcnt vmcnt(0)" ::: "memory");
    __builtin_amdgcn_s_barrier();
    asm volatile("" ::: "memory");

    for (int kt = 0; kt < nt; ++kt) {
        const int cur = kt & 1;
        const bool more = (kt + 1 < nt);
        if (more) issue(cur ^ 1, kt + 1);
        bf16x8 bf[4], a0, a1, a2, a3;
#pragma unroll
        for (int fn = 0; fn < 4; fn++) bf[fn] = ldB(cur, fn);
        a0 = ldA(cur, 0); a1 = ldA(cur, 1); a2 = ldA(cur, 2); a3 = ldA(cur, 3);
        asm volatile("s_waitcnt lgkmcnt(0)" ::: "memory");
        __builtin_amdgcn_s_setprio(1);
#pragma unroll
        for (int fn = 0; fn < 4; fn++) {
            acc[0][fn] = __builtin_amdgcn_mfma_f32_16x16x32_bf16(a0, bf[fn], acc[0][fn], 0, 0, 0);
            acc[1][fn] = __builtin_amdgcn_mfma_f32_16x16x32_bf16(a1, bf[fn], acc[1][fn], 0, 0, 0);
            acc[2][fn] = __builtin_amdgcn_mfma_f32_16x16x32_bf16(a2, bf[fn], acc[2][fn], 0, 0, 0);
            acc[3][fn] = __builtin_amdgcn_mfma_f32_16x16x32_bf16(a3, bf[fn], acc[3][fn], 0, 0, 0);
        }
        __builtin_amdgcn_s_setprio(0);
        a0 = ldA(cur, 4); a1 = ldA(cur, 5); a2 = ldA(cur, 6); a3 = ldA(cur, 7);
        asm volatile("s_waitcnt lgkmcnt(0)" ::: "memory");
        __builtin_amdgcn_s_setprio(1);
#pragma unroll
        for (int fn = 0; fn < 4; fn++) {
            acc[4][fn] = __builtin_amdgcn_mfma_f32_16x16x32_bf16(a0, bf[fn], acc[4][fn], 0, 0, 0);
            acc[5][fn] = __builtin_amdgcn_mfma_f32_16x16x32_bf16(a1, bf[fn], acc[5][fn], 0, 0, 0);
            acc[6][fn] = __builtin_amdgcn_mfma_f32_16x16x32_bf16(a2, bf[fn], acc[6][fn], 0, 0, 0);
            acc[7][fn] = __builtin_amdgcn_mfma_f32_16x16x32_bf16(a3, bf[fn], acc[7][fn], 0, 0, 0);
        }
        __builtin_amdgcn_s_setprio(0);
        if (more) {
            asm volatile("s_waitcnt vmcnt(0)" ::: "memory");
            __builtin_amdgcn_s_barrier();
            asm volatile("" ::: "memory");
        }
    }

    // nontemporal epilogue stores (output never re-read on device)
#pragma unroll
    for (int fm = 0; fm < 8; fm++) {
#pragma unroll
        for (int fn = 0; fn < 4; fn++) {
            const int col = tn * 256 + wn * 64 + fn * 16 + lo;
#pragma unroll
            for (int r = 0; r < 4; r++) {
                const long row = (long)tm * 256 + wm * 128 + fm * 16 + hi * 4 + r;
                if (col < NREC)
                    __builtin_nontemporal_store(acc[fm][fn][r] + bias[col],
                                                &Fout[row * (long)NREC + col]);
            }
        }
    }
}

// ---------------- stage C: projections + scatter ----------------
__global__ __launch_bounds__(256)
void k_proj(const unsigned short* __restrict__ h_rna,
            const unsigned short* __restrict__ h_atac,
            const float* __restrict__ W_rmu, const float* __restrict__ b_rmu,
            const float* __restrict__ W_rvar, const float* __restrict__ b_rvar,
            const float* __restrict__ W_amu, const float* __restrict__ b_amu,
            const float* __restrict__ W_avar, const float* __restrict__ b_avar,
            const int* __restrict__ idx_rna, const int* __restrict__ idx_atac,
            float* __restrict__ mu0, float* __restrict__ var0,
            float* __restrict__ mu1, float* __restrict__ var1,
            float* __restrict__ mflag)
{
    __shared__ __align__(16) unsigned short hsh[4][2][NH];
    const int wave = threadIdx.x >> 6, lane = threadIdx.x & 63;
    const long i = (long)blockIdx.x * 4 + wave;
    *(uint4*)&hsh[wave][0][lane * 8] = *(const uint4*)(h_rna  + i * NH + lane * 8);
    *(uint4*)&hsh[wave][1][lane * 8] = *(const uint4*)(h_atac + i * NH + lane * 8);
    __syncthreads();
    const int mod = lane >> 5, oo = lane & 31;
    const int isv = oo >> 4, o = oo & 15;
    const float *W, *bias;
    if (mod == 0) { W = isv ? W_rvar : W_rmu; bias = isv ? b_rvar : b_rmu; }
    else          { W = isv ? W_avar : W_amu; bias = isv ? b_avar : b_amu; }
    const unsigned short* hr = hsh[wave][mod];
    const float* wrow = W + o * NH;
    float a = 0.f;
#pragma unroll 4
    for (int k = 0; k < NH; k += 4) {
        float4 w = *(const float4*)(wrow + k);
        a += bf2f(hr[k]) * w.x + bf2f(hr[k+1]) * w.y + bf2f(hr[k+2]) * w.z + bf2f(hr[k+3]) * w.w;
    }
    a += bias[o];
    const int tgt = (mod == 0) ? idx_rna[i] : idx_atac[i];
    float* mu  = mod ? mu1  : mu0;
    float* var = mod ? var1 : var0;
    if (!isv) mu[(long)tgt * 16 + o] = a;
    else      var[(long)tgt * 16 + o] = expf(a);
    if (oo == 0) mflag[(long)mod * NS + tgt] = 1.f;
}

// ---------------- stage C: PoE combine + q + decoder hidden ----------------
__global__ __launch_bounds__(256)
void k_combine(const float* __restrict__ mu0, const float* __restrict__ var0,
               const float* __restrict__ mu1, const float* __restrict__ var1,
               const float* __restrict__ mflag,
               const float* __restrict__ eps, const float* __restrict__ cluster,
               const float* __restrict__ W_d1,
               const float* __restrict__ s_d, const float* __restrict__ t_d,
               float* __restrict__ o_zmu, float* __restrict__ o_zvar,
               float* __restrict__ o_z, float* __restrict__ o_q,
               unsigned short* __restrict__ h_d)
{
    __shared__ float zsh[4][16];
    const int wave = threadIdx.x >> 6, lane = threadIdx.x & 63;
    const long i = (long)blockIdx.x * 4 + wave;
    if (lane < 16) {
        const int d = lane;
        const float f0 = mflag[i], f1 = mflag[NS + i];
        float ts = 1.f, num = 0.f;
        if (f0 != 0.f) { float iv = 1.f / var0[i*16+d]; ts += iv; num += mu0[i*16+d] * iv; }
        if (f1 != 0.f) { float iv = 1.f / var1[i*16+d]; ts += iv; num += mu1[i*16+d] * iv; }
        const float zm = num / ts, zv = 1.f / ts;
        const float z = zm + zv * eps[i*16+d];
        o_zmu[i*16+d] = zm; o_zvar[i*16+d] = zv; o_z[i*16+d] = z;
        zsh[wave][d] = z;
    }
    __syncthreads();
    float zreg[16];
#pragma unroll
    for (int d = 0; d < 16; d++) zreg[d] = zsh[wave][d];
    float qk = 0.f;
    if (lane < KC) {
        float d2 = 0.f;
#pragma unroll
        for (int d = 0; d < 16; d++) { float df = zreg[d] - cluster[lane*16+d]; d2 += df*df; }
        qk = 1.f / (1.f + d2);
    }
    float ssum = qk;
#pragma unroll
    for (int off = 16; off > 0; off >>= 1) ssum += __shfl_xor(ssum, off, 32);
    if (lane < KC) o_q[i * KC + lane] = qk / ssum;
#pragma unroll
    for (int j = 0; j < 8; j++) {
        const int c = lane + 64 * j;
        float a = 0.f;
#pragma unroll
        for (int d = 0; d < 16; d += 4) {
            float4 w = *(const float4*)(W_d1 + c * 16 + d);
            a += zreg[d] * w.x + zreg[d+1] * w.y + zreg[d+2] * w.z + zreg[d+3] * w.w;
        }
        a = fmaxf(a * s_d[c] + t_d[c], 0.f);
        h_d[i * NH + c] = f2bf(a);
    }
}

// ---------------- launcher ----------------
extern "C" void kernel_launch(void* const* d_in, const int* in_sizes, int n_in,
                              void* d_out, int out_size, void* d_ws, size_t ws_size,
                              hipStream_t stream)
{
    const float* rna    = (const float*)d_in[0];
    const float* atac   = (const float*)d_in[1];
    const int*   i_rna  = (const int*)d_in[2];
    const int*   i_atac = (const int*)d_in[3];
    const float* eps    = (const float*)d_in[4];
    const float* W_r1   = (const float*)d_in[5];
    const float* b_r1   = (const float*)d_in[6];
    const float* g_r    = (const float*)d_in[7];
    const float* be_r   = (const float*)d_in[8];
    const float* m_r    = (const float*)d_in[9];
    const float* v_r    = (const float*)d_in[10];
    const float* W_rmu  = (const float*)d_in[11];
    const float* b_rmu  = (const float*)d_in[12];
    const float* W_rvar = (const float*)d_in[13];
    const float* b_rvar = (const float*)d_in[14];
    const float* W_a1   = (const float*)d_in[15];
    const float* b_a1   = (const float*)d_in[16];
    const float* g_a    = (const float*)d_in[17];
    const float* be_a   = (const float*)d_in[18];
    const float* m_a    = (const float*)d_in[19];
    const float* v_a    = (const float*)d_in[20];
    const float* W_amu  = (const float*)d_in[21];
    const float* b_amu  = (const float*)d_in[22];
    const float* W_avar = (const float*)d_in[23];
    const float* b_avar = (const float*)d_in[24];
    const float* W_d1   = (const float*)d_in[25];
    const float* b_d1   = (const float*)d_in[26];
    const float* g_d    = (const float*)d_in[27];
    const float* be_d   = (const float*)d_in[28];
    const float* m_d    = (const float*)d_in[29];
    const float* v_d    = (const float*)d_in[30];
    const float* W_d4   = (const float*)d_in[31];
    const float* b_d4   = (const float*)d_in[32];
    const float* clus   = (const float*)d_in[33];
    (void)in_sizes; (void)n_in; (void)out_size;

    char* w = (char*)d_ws;
    size_t off = 0;
    auto carve = [&](size_t bytes) { void* p = w + off; off += (bytes + 255) & ~(size_t)255; return p; };
    unsigned short* wr1b  = (unsigned short*)carve((size_t)NH * NF1c * 2);
    unsigned short* wa1b  = (unsigned short*)carve((size_t)NH * NF2c * 2);
    unsigned short* wd4b  = (unsigned short*)carve((size_t)NRECP * NH * 2);
    unsigned short* hrna  = (unsigned short*)carve((size_t)NS * NH * 2);
    unsigned short* hatac = (unsigned short*)carve((size_t)NS * NH * 2);
    unsigned short* hd    = (unsigned short*)carve((size_t)NS * NH * 2);
    float* mu0   = (float*)carve((size_t)NS * 16 * 4);
    float* var0  = (float*)carve((size_t)NS * 16 * 4);
    float* mu1   = (float*)carve((size_t)NS * 16 * 4);
    float* var1  = (float*)carve((size_t)NS * 16 * 4);
    float* mflag = (float*)carve((size_t)2 * NS * 4);
    float* st    = (float*)carve((size_t)6 * NH * 4);
    if (off > ws_size) return;  // insufficient workspace -> loud validation failure

    // st layout: [r: s,t][a: s,t][d: s,t]
    float* s_r = st;              float* t_r = st + NH;
    float* s_a = st + 2 * NH;     float* t_a = st + 3 * NH;
    float* s_d = st + 4 * NH;     float* t_d = st + 5 * NH;

    float* out    = (float*)d_out;
    float* o_rec  = out;
    float* o_zmu  = out + (size_t)NS * NREC;
    float* o_zvar = o_zmu + (size_t)NS * 16;
    float* o_z    = o_zvar + (size_t)NS * 16;
    float* o_q    = o_z + (size_t)NS * 16;

    dim3 blk(256);
    // consolidated prep: one launch replaces 3x cvt + 3x prep_st + zero
    k_prep<<<4096, blk, 0, stream>>>(W_r1, wr1b, W_a1, wa1b, W_d4, wd4b,
                                     g_r, be_r, m_r, v_r, b_r1,
                                     g_a, be_a, m_a, v_a, b_a1,
                                     g_d, be_d, m_d, v_d, b_d1,
                                     st, mflag);
    // encoder GEMMs (r4-exact): BK=64, ntn=4, 512 blocks each
    k_gemm<<<512, blk, 0, stream>>>(rna,  wr1b, NF1c, NH, 4, s_r, t_r, hrna);
    k_gemm<<<512, blk, 0, stream>>>(atac, wa1b, NF2c, NH, 4, s_a, t_a, hatac);
    k_proj<<<NS / 4, blk, 0, stream>>>(hrna, hatac, W_rmu, b_rmu, W_rvar, b_rvar,
                                       W_amu, b_amu, W_avar, b_avar, i_rna, i_atac,
                                       mu0, var0, mu1, var1, mflag);
    k_combine<<<NS / 4, blk, 0, stream>>>(mu0, var0, mu1, var1, mflag, eps, clus,
                                          W_d1, s_d, t_d, o_zmu, o_zvar, o_z, o_q, hd);
    // recon: 256x256 tile, 3008 blocks of 512 threads (r15-exact)
    k_rec256<<<3008, dim3(512), 0, stream>>>(hd, wd4b, b_d4, o_rec);
}